// Round 5
// baseline (111919.824 us; speedup 1.0000x reference)
//
#include <hip/hip_runtime.h>
#include <hip/hip_bf16.h>

#define T_ 256
#define B_ 64
#define NWG 128

__device__ __forceinline__ float sigm(float x){ return 1.0f/(1.0f + expf(-x)); }

// ---------------- prep: E (f32), mask, stepflag, barrier init ----------------
__global__ void d_prep(const int* __restrict__ in0, const int* __restrict__ in1,
                       const int* __restrict__ mtok,
                       const float* __restrict__ emb0, const float* __restrict__ emb1,
                       float* __restrict__ E, float* __restrict__ mask,
                       unsigned* __restrict__ stepflag, unsigned* __restrict__ bar)
{
  int gid = blockIdx.x*blockDim.x + threadIdx.x;
  int gsz = gridDim.x*blockDim.x;
  int mt = mtok[0];
  for (int i=gid; i<T_*B_*512; i+=gsz){
    int m = i>>9, k = i&511;
    int t = m>>6, b = m&63;
    float v;
    if (k < 256) v = emb0[(size_t)in0[b*T_+t]*256 + k];
    else         v = emb1[(size_t)in1[b*T_+t]*256 + (k-256)];
    E[i] = v;
  }
  for (int i=gid; i<T_*B_; i+=gsz){
    int t = i>>6, b = i&63;
    mask[i] = (in0[b*T_+t] == mt) ? 1.0f : 0.0f;
  }
  for (int i=gid; i<T_; i+=gsz){
    unsigned f = 0;
    for (int b=0;b<B_;b++) f |= (in0[b*T_+i] == mt) ? 1u : 0u;
    stepflag[i] = f;
  }
  if (gid == 0){ bar[0] = 0; bar[32] = 0; }
}

// ---------------- grid barrier: full agent fences on both sides ----------------
__device__ __forceinline__ void gbarrier(unsigned* bar, unsigned gen){
  __threadfence();            // every thread: publish
  __syncthreads();
  if (threadIdx.x == 0){
    unsigned old = __hip_atomic_fetch_add(&bar[0], 1u, __ATOMIC_ACQ_REL, __HIP_MEMORY_SCOPE_AGENT);
    if (old == gen*NWG + (NWG-1)){
      __hip_atomic_store(&bar[32], gen+1u, __ATOMIC_RELEASE, __HIP_MEMORY_SCOPE_AGENT);
    } else {
      while (__hip_atomic_load(&bar[32], __ATOMIC_ACQUIRE, __HIP_MEMORY_SCOPE_AGENT) < gen+1u)
        __builtin_amdgcn_s_sleep(2);
    }
  }
  __syncthreads();
  __threadfence();            // every thread: acquire side
}

// ---------------- persistent recurrence: WG j owns h-dims [4j, 4j+4) ----------------
// Pure f32 VALU. Phase A: gates_low = [x_t ; h_l ; h_h](1536) . [Wih_low_x ; Whh_low ; Wih_low_h]^T
// Phase B (only on flagged steps): gates_high = [h_l_new ; h_h](1024) . [Wih_high ; Whh_high]^T
__launch_bounds__(256)
__global__ void d_recur(const float* __restrict__ h_low0, const float* __restrict__ c_low0,
                        const float* __restrict__ h_high0, const float* __restrict__ c_high0,
                        const float* __restrict__ Wihl, const float* __restrict__ bihl,
                        const float* __restrict__ Whhl, const float* __restrict__ bhhl,
                        const float* __restrict__ Wihh, const float* __restrict__ bihh,
                        const float* __restrict__ Whhh, const float* __restrict__ bhhh,
                        const float* __restrict__ E, const float* __restrict__ mask,
                        const unsigned* __restrict__ stepflag,
                        float* hl_buf, float* hh_buf, float* __restrict__ hseq,
                        unsigned* bar, float* __restrict__ outS)
{
  __shared__ float hC[64*132];   // staged A-vector chunk [64 b][128 k]
  __shared__ float gb[16*64];    // gate partials [16 rows][64 b]
  __shared__ float cl[64*4];
  __shared__ float ch[64*4];
  const int tid = threadIdx.x;
  const int j = blockIdx.x;
  const int d0 = j*4;            // this WG's 4 h-dims
  const int b  = tid & 63;       // lane = batch
  const int np = tid >> 6;       // wave = gate (i,f,g,o)

  // init cell states (LDS, WG-local) and h buffers (slot 0, global)
  for (int i=tid; i<256; i+=256){
    int bb = i>>2, dd = i&3;
    cl[i] = c_low0[bb*512 + d0 + dd];
    ch[i] = c_high0[bb*512 + d0 + dd];
  }
  for (int i=tid; i<256; i+=256){
    int gi = j*256 + i;
    hl_buf[gi] = h_low0[gi];
    hh_buf[gi] = h_high0[gi];
  }
  unsigned gen = 0;
  gbarrier(bar, gen); gen++;

  int hs = 0;
  for (int t=0; t<T_; t++){
    const int rl = t&1, wl = rl^1;
    const float* hlr = hl_buf + rl*32768;
    const float* hhr = hh_buf + hs*32768;

    // ---- phase A: 12 chunks of 128 k over [x_t(512); h_l(512); h_h(512)] ----
    float acc[4] = {0.f,0.f,0.f,0.f};
    for (int c=0; c<12; c++){
      __syncthreads();
      for (int e4=tid; e4<2048; e4+=256){
        int row = e4>>5, kk4 = (e4&31)*4;
        const float* srcp;
        if (c < 4)      srcp = E   + ((size_t)(t*64) + row)*512 + c*128;
        else if (c < 8) srcp = hlr + (size_t)row*512 + (c-4)*128;
        else            srcp = hhr + (size_t)row*512 + (c-8)*128;
        *(float4*)&hC[row*132 + kk4] = *(const float4*)(srcp + kk4);
      }
      __syncthreads();
      #pragma unroll
      for (int i=0;i<4;i++){
        int ng = np*512 + d0 + i;
        const float* wp;
        if (c < 4)      wp = Wihl + (size_t)ng*1024 + c*128;
        else if (c < 8) wp = Whhl + (size_t)ng*512  + (c-4)*128;
        else            wp = Wihl + (size_t)ng*1024 + 512 + (c-8)*128;
        float a = acc[i];
        for (int k4=0;k4<32;k4++){
          float4 hv = *(const float4*)&hC[b*132 + k4*4];
          float4 wv = *(const float4*)(wp + k4*4);
          a = fmaf(hv.x, wv.x, a);
          a = fmaf(hv.y, wv.y, a);
          a = fmaf(hv.z, wv.z, a);
          a = fmaf(hv.w, wv.w, a);
        }
        acc[i] = a;
      }
    }
    #pragma unroll
    for (int i=0;i<4;i++) gb[(np*4+i)*64 + b] = acc[i];
    __syncthreads();
    {
      const int dd = np;  // wave = dim index for elementwise (4 waves x 64 b = 256)
      int d = d0 + dd;
      float g_i = gb[(0 +dd)*64 + b] + bihl[d]        + bhhl[d];
      float g_f = gb[(4 +dd)*64 + b] + bihl[512 + d]  + bhhl[512 + d];
      float g_g = gb[(8 +dd)*64 + b] + bihl[1024 + d] + bhhl[1024 + d];
      float g_o = gb[(12+dd)*64 + b] + bihl[1536 + d] + bhhl[1536 + d];
      float c_ = sigm(g_f)*cl[b*4+dd] + sigm(g_i)*tanhf(g_g);
      float h_ = sigm(g_o)*tanhf(c_);
      cl[b*4+dd] = c_;
      hl_buf[wl*32768 + b*512 + d] = h_;
      hseq[((size_t)(t*64) + b)*512 + d] = h_;
    }
    gbarrier(bar, gen); gen++;

    // ---- phase B: high cell, only on steps where any batch is masked ----
    if (stepflag[t]){
      const float* hln = hl_buf + wl*32768;
      float accB[4] = {0.f,0.f,0.f,0.f};
      for (int c=0; c<8; c++){
        __syncthreads();
        for (int e4=tid; e4<2048; e4+=256){
          int row = e4>>5, kk4 = (e4&31)*4;
          const float* srcp = (c < 4) ? (hln + (size_t)row*512 + c*128)
                                      : (hhr + (size_t)row*512 + (c-4)*128);
          *(float4*)&hC[row*132 + kk4] = *(const float4*)(srcp + kk4);
        }
        __syncthreads();
        #pragma unroll
        for (int i=0;i<4;i++){
          int ng = np*512 + d0 + i;
          const float* wp = (c < 4) ? (Wihh + (size_t)ng*512 + c*128)
                                    : (Whhh + (size_t)ng*512 + (c-4)*128);
          float a = accB[i];
          for (int k4=0;k4<32;k4++){
            float4 hv = *(const float4*)&hC[b*132 + k4*4];
            float4 wv = *(const float4*)(wp + k4*4);
            a = fmaf(hv.x, wv.x, a);
            a = fmaf(hv.y, wv.y, a);
            a = fmaf(hv.z, wv.z, a);
            a = fmaf(hv.w, wv.w, a);
          }
          accB[i] = a;
        }
      }
      #pragma unroll
      for (int i=0;i<4;i++) gb[(np*4+i)*64 + b] = accB[i];
      __syncthreads();
      {
        const int dd = np;
        int d = d0 + dd;
        float g_i = gb[(0 +dd)*64 + b] + bihh[d]        + bhhh[d];
        float g_f = gb[(4 +dd)*64 + b] + bihh[512 + d]  + bhhh[512 + d];
        float g_g = gb[(8 +dd)*64 + b] + bihh[1024 + d] + bhhh[1024 + d];
        float g_o = gb[(12+dd)*64 + b] + bihh[1536 + d] + bhhh[1536 + d];
        float ct = sigm(g_f)*ch[b*4+dd] + sigm(g_i)*tanhf(g_g);
        float ht = sigm(g_o)*tanhf(ct);
        float m  = mask[t*64 + b];
        float hold = hh_buf[hs*32768 + b*512 + d];
        hh_buf[(hs^1)*32768 + b*512 + d] = m*ht + (1.0f-m)*hold;
        ch[b*4+dd] = m*ct + (1.0f-m)*ch[b*4+dd];
      }
      gbarrier(bar, gen); gen++;
      hs ^= 1;
    }
  }
  // final states (h_l ended in slot 0 after t=255) -> f32 outputs
  {
    const int dd = np;
    int d = d0 + dd;
    int gi = b*512 + d;
    outS[gi]          = hl_buf[gi];
    outS[32768 + gi]  = cl[b*4+dd];
    outS[65536 + gi]  = hh_buf[hs*32768 + gi];
    outS[98304 + gi]  = ch[b*4+dd];
  }
}

// ---------------- decoder: out[(b*T+t)][n] = hseq[m=t*64+b] . Wdec[n] + bias[n] ----------------
__launch_bounds__(256)
__global__ void d_dec(const float* __restrict__ A, const float* __restrict__ W,
                      const float* __restrict__ bias, float* __restrict__ out, int N)
{
  __shared__ float hC[64*132];
  const int tid = threadIdx.x;
  const int m0 = blockIdx.x*64, n0 = blockIdx.y*64;
  const int msub = tid&63, wv_ = tid>>6;
  float acc[16] = {};
  for (int c=0; c<4; c++){
    __syncthreads();
    for (int e4=tid; e4<2048; e4+=256){
      int row = e4>>5, kk4 = (e4&31)*4;
      *(float4*)&hC[row*132 + kk4] = *(const float4*)(A + ((size_t)(m0+row))*512 + c*128 + kk4);
    }
    __syncthreads();
    for (int k4=0;k4<32;k4++){
      float4 av = *(const float4*)&hC[msub*132 + k4*4];
      #pragma unroll
      for (int jj=0;jj<16;jj++){
        int n = n0 + wv_*16 + jj;
        float4 wv = *(const float4*)&W[(size_t)n*512 + c*128 + k4*4];
        acc[jj] = fmaf(av.x, wv.x, acc[jj]);
        acc[jj] = fmaf(av.y, wv.y, acc[jj]);
        acc[jj] = fmaf(av.z, wv.z, acc[jj]);
        acc[jj] = fmaf(av.w, wv.w, acc[jj]);
      }
    }
  }
  int m = m0 + msub;
  int t = m>>6, bb = m&63;
  #pragma unroll
  for (int jj=0;jj<16;jj++){
    int n = n0 + wv_*16 + jj;
    out[((size_t)bb*T_ + t)*N + n] = acc[jj] + bias[n];
  }
}

extern "C" void kernel_launch(void* const* d_in, const int* in_sizes, int n_in,
                              void* d_out, int out_size, void* d_ws, size_t ws_size,
                              hipStream_t stream)
{
  const int*   in0    = (const int*)  d_in[0];
  const int*   in1    = (const int*)  d_in[1];
  const float* hl0    = (const float*)d_in[2];
  const float* cl0    = (const float*)d_in[3];
  const float* hh0    = (const float*)d_in[4];
  const float* ch0    = (const float*)d_in[5];
  const int*   mtok   = (const int*)  d_in[6];
  const float* emb0   = (const float*)d_in[7];
  const float* emb1   = (const float*)d_in[8];
  const float* Wihl_f = (const float*)d_in[9];
  const float* bihl   = (const float*)d_in[10];
  const float* Whhl_f = (const float*)d_in[11];
  const float* bhhl   = (const float*)d_in[12];
  const float* Wihh_f = (const float*)d_in[13];
  const float* bihh   = (const float*)d_in[14];
  const float* Whhh_f = (const float*)d_in[15];
  const float* bhhh   = (const float*)d_in[16];
  const float* Wd0_f  = (const float*)d_in[17];
  const float* bd0    = (const float*)d_in[18];
  const float* Wd1_f  = (const float*)d_in[19];
  const float* bd1    = (const float*)d_in[20];

  // d_out is FLOAT (reference outputs are f32). Layout (floats):
  //   dec0 [B,T,2048] @ 0          (33,554,432)
  //   dec1 [B,T,512]  @ 33554432   ( 8,388,608)
  //   h_l,c_l,h_h,c_h @ 41943040   (4 x 32768)
  float* dout = (float*)d_out;

  // E (32 MB f32) lives in dec0's region of d_out: dead before d_dec writes dec0.
  float* E = dout;

  char* ws = (char*)d_ws;
  float*    hseq = (float*)   (ws + 0);            // [16384][512] f32, 32 MiB
  float*    hlb  = (float*)   (ws + 33554432);     // [2][64][512] f32
  float*    hhb  = (float*)   (ws + 33816576);     // [2][64][512] f32
  float*    mask = (float*)   (ws + 34078720);     // [256][64]
  unsigned* sflg = (unsigned*)(ws + 34144256);     // [256]
  unsigned* bar  = (unsigned*)(ws + 34145280);

  d_prep<<<2048, 256, 0, stream>>>(in0, in1, mtok, emb0, emb1, E, mask, sflg, bar);
  d_recur<<<NWG, 256, 0, stream>>>(hl0, cl0, hh0, ch0,
                                   Wihl_f, bihl, Whhl_f, bhhl,
                                   Wihh_f, bihh, Whhh_f, bhhh,
                                   E, mask, sflg, hlb, hhb, hseq, bar,
                                   dout + 41943040);
  dim3 g0(256, 32);
  d_dec<<<g0, 256, 0, stream>>>(hseq, Wd0_f, bd0, dout, 2048);
  dim3 g1(256, 8);
  d_dec<<<g1, 256, 0, stream>>>(hseq, Wd1_f, bd1, dout + 33554432, 512);
}

// Round 6
// 2692.550 us; speedup vs baseline: 41.5665x; 41.5665x over previous
//
#include <hip/hip_runtime.h>
#include <hip/hip_bf16.h>

#define T_ 256
#define B_ 64
#define NWG 64

typedef __attribute__((ext_vector_type(8))) short bf16x8;
typedef __attribute__((ext_vector_type(4))) float f32x4;

__device__ __forceinline__ float bf2f(unsigned short u){
  unsigned int i = ((unsigned int)u) << 16;
  float f; __builtin_memcpy(&f, &i, 4); return f;
}
__device__ __forceinline__ unsigned short f2bf(float f){
  __hip_bfloat16 h = __float2bfloat16(f);
  unsigned short u; __builtin_memcpy(&u, &h, 2); return u;
}
__device__ __forceinline__ float sigm(float x){ return 1.0f/(1.0f + expf(-x)); }

// coherent (agent-scope, sc-flagged) accessors for cross-WG state.
// These are per-access coherent: NO cache-wide invalidates (unlike __threadfence,
// which emitted buffer_wbl2/inv per call and caused r5's 162 GB HBM thrash).
__device__ __forceinline__ bf16x8 ld_h8(const unsigned short* p){
  union { unsigned long long q[2]; bf16x8 v; } u;
  u.q[0] = __hip_atomic_load((const unsigned long long*)p,       __ATOMIC_RELAXED, __HIP_MEMORY_SCOPE_AGENT);
  u.q[1] = __hip_atomic_load((const unsigned long long*)(p + 4), __ATOMIC_RELAXED, __HIP_MEMORY_SCOPE_AGENT);
  return u.v;
}
__device__ __forceinline__ void st_h2(unsigned short* p, unsigned short lo, unsigned short hi){
  unsigned v = (unsigned)lo | ((unsigned)hi << 16);
  __hip_atomic_store((unsigned*)p, v, __ATOMIC_RELAXED, __HIP_MEMORY_SCOPE_AGENT);
}
__device__ __forceinline__ unsigned ld_h2(const unsigned short* p){
  return __hip_atomic_load((const unsigned*)p, __ATOMIC_RELAXED, __HIP_MEMORY_SCOPE_AGENT);
}

// ---------------- prep: weight bf16 conversion, embedding concat, mask/flags ----------------
__global__ void k_prep(const int* __restrict__ in0, const int* __restrict__ in1,
                       const int* __restrict__ mtok,
                       const float* __restrict__ emb0, const float* __restrict__ emb1,
                       const float* __restrict__ Wih_low, const float* __restrict__ Whh_low_f,
                       const float* __restrict__ Wih_high_f, const float* __restrict__ Whh_high_f,
                       const float* __restrict__ Wdec0_f, const float* __restrict__ Wdec1_f,
                       unsigned short* __restrict__ W0, unsigned short* __restrict__ Wlh,
                       unsigned short* __restrict__ Whhl, unsigned short* __restrict__ Wihh,
                       unsigned short* __restrict__ Whhh, unsigned short* __restrict__ Wd0,
                       unsigned short* __restrict__ Wd1, unsigned short* __restrict__ E,
                       float* __restrict__ mask, unsigned* __restrict__ stepflag,
                       unsigned* __restrict__ bar)
{
  int gid = blockIdx.x*blockDim.x + threadIdx.x;
  int gsz = gridDim.x*blockDim.x;
  for (int i=gid; i<2048*512; i+=gsz){
    int r = i>>9, c = i&511;
    W0[i]   = f2bf(Wih_low[(size_t)r*1024 + c]);
    Wlh[i]  = f2bf(Wih_low[(size_t)r*1024 + 512 + c]);
    Whhl[i] = f2bf(Whh_low_f[i]);
    Wihh[i] = f2bf(Wih_high_f[i]);
    Whhh[i] = f2bf(Whh_high_f[i]);
    Wd0[i]  = f2bf(Wdec0_f[i]);
  }
  for (int i=gid; i<512*512; i+=gsz) Wd1[i] = f2bf(Wdec1_f[i]);
  int mt = mtok[0];
  for (int i=gid; i<T_*B_*512; i+=gsz){
    int m = i>>9, k = i&511;
    int t = m>>6, b = m&63;
    float v;
    if (k < 256) v = emb0[(size_t)in0[b*T_+t]*256 + k];
    else         v = emb1[(size_t)in1[b*T_+t]*256 + (k-256)];
    E[i] = f2bf(v);
  }
  for (int i=gid; i<T_*B_; i+=gsz){
    int t = i>>6, b = i&63;
    mask[i] = (in0[b*T_+t] == mt) ? 1.0f : 0.0f;
  }
  for (int i=gid; i<T_; i+=gsz){
    unsigned f = 0;
    for (int b=0;b<B_;b++) f |= (in0[b*T_+i] == mt) ? 1u : 0u;
    stepflag[i] = f;
  }
  if (gid == 0){ bar[0] = 0; }
}

// ---------------- bf16 MFMA GEMM: out[M,N] = A[M,512] @ W[N,512]^T + bias ----------------
// mode 0: out bf16 at [m*N+n] (m = t*64+b order preserved)   [xW path]
// mode 1: out f32  at [(b*256+t)*N+n]                        [decoder path]
__launch_bounds__(256)
__global__ void k_gemm(const unsigned short* __restrict__ A,
                       const unsigned short* __restrict__ W,
                       const float* __restrict__ bias1, const float* __restrict__ bias2,
                       unsigned short* __restrict__ out16, float* __restrict__ out32,
                       int N, int mode)
{
  __shared__ unsigned short As[128*40];
  __shared__ unsigned short Bs[128*40];
  const int tid = threadIdx.x;
  const int m0 = blockIdx.x*128, n0 = blockIdx.y*128;
  const int wid = tid>>6, lane = tid&63;
  const int wm = (wid>>1)*64, wn = (wid&1)*64;
  const int lr = lane&15, lk = lane>>4;
  f32x4 acc[4][4] = {};
  for (int k0=0; k0<512; k0+=32){
    __syncthreads();
    #pragma unroll
    for (int i=0;i<2;i++){
      int eb = tid + 256*i;
      int row = eb>>2, kb = eb&3;
      *(bf16x8*)&As[row*40 + kb*8] = *(const bf16x8*)&A[(size_t)(m0+row)*512 + k0 + kb*8];
      *(bf16x8*)&Bs[row*40 + kb*8] = *(const bf16x8*)&W[(size_t)(n0+row)*512 + k0 + kb*8];
    }
    __syncthreads();
    bf16x8 af[4], bff[4];
    #pragma unroll
    for (int i=0;i<4;i++){
      af[i]  = *(const bf16x8*)&As[(wm + i*16 + lr)*40 + lk*8];
      bff[i] = *(const bf16x8*)&Bs[(wn + i*16 + lr)*40 + lk*8];
    }
    #pragma unroll
    for (int mi=0;mi<4;mi++)
      #pragma unroll
      for (int ni=0;ni<4;ni++)
        acc[mi][ni] = __builtin_amdgcn_mfma_f32_16x16x32_bf16(af[mi], bff[ni], acc[mi][ni], 0,0,0);
  }
  #pragma unroll
  for (int mi=0;mi<4;mi++){
    #pragma unroll
    for (int ni=0;ni<4;ni++){
      int n = n0 + wn + ni*16 + lr;
      float bb = bias1 ? bias1[n] : 0.0f;
      if (bias2) bb += bias2[n];
      #pragma unroll
      for (int r=0;r<4;r++){
        int m = m0 + wm + mi*16 + lk*4 + r;
        float v = acc[mi][ni][r] + bb;
        if (mode == 0){
          out16[(size_t)m*N + n] = f2bf(v);
        } else {
          int t = m>>6, b = m&63;
          out32[((size_t)b*T_ + t)*N + n] = v;
        }
      }
    }
  }
}

// ---------------- grid barrier: atomic counter only, NO threadfence ----------------
// All mutable cross-WG data moves via sc-flagged atomics (coherent per-access),
// so the barrier needs only ordering: ACQ_REL RMW publishes, relaxed spin,
// one ACQUIRE load on exit. Counter is monotone across generations (no reset).
__device__ __forceinline__ void gbarrier(unsigned* bar, unsigned gen){
  __syncthreads();
  if (threadIdx.x == 0){
    __hip_atomic_fetch_add(&bar[0], 1u, __ATOMIC_ACQ_REL, __HIP_MEMORY_SCOPE_AGENT);
    while (__hip_atomic_load(&bar[0], __ATOMIC_RELAXED, __HIP_MEMORY_SCOPE_AGENT) < (gen+1u)*NWG)
      __builtin_amdgcn_s_sleep(2);
    (void)__hip_atomic_load(&bar[0], __ATOMIC_ACQUIRE, __HIP_MEMORY_SCOPE_AGENT);
  }
  __syncthreads();
}

// hht[b][n] = Wlh_rows(n) . h_h[b,:]   (WG-local cached term, recomputed on flagged steps)
__device__ __forceinline__ void compute_hht(const unsigned short* __restrict__ hh,
                                            const unsigned short* __restrict__ Wlh,
                                            float* hht, int d0, int mb, int lr, int lk)
{
  bf16x8 av[16];
  #pragma unroll
  for (int ks=0;ks<16;ks++)
    av[ks] = ld_h8(&hh[(mb+lr)*512 + ks*32 + lk*8]);
  f32x4 a0 = {0.f,0.f,0.f,0.f}, a1 = {0.f,0.f,0.f,0.f};
  int g0 = ((lr>>3)<<9) + d0 + (lr&7);
  int g1 = 1024 + g0;
  #pragma unroll
  for (int ks=0;ks<16;ks++){
    bf16x8 b0 = *(const bf16x8*)&Wlh[(size_t)g0*512 + ks*32 + lk*8];
    bf16x8 b1 = *(const bf16x8*)&Wlh[(size_t)g1*512 + ks*32 + lk*8];
    a0 = __builtin_amdgcn_mfma_f32_16x16x32_bf16(av[ks], b0, a0, 0,0,0);
    a1 = __builtin_amdgcn_mfma_f32_16x16x32_bf16(av[ks], b1, a1, 0,0,0);
  }
  #pragma unroll
  for (int r=0;r<4;r++){
    int b = mb + lk*4 + r;
    hht[b*33 + lr]      = a0[r];
    hht[b*33 + 16 + lr] = a1[r];
  }
}

// ---------------- persistent recurrence: 64 WGs, WG j owns h-dims [8j, 8j+8) ----------------
__launch_bounds__(256)
__global__ void k_recur(const float* __restrict__ h_low0, const float* __restrict__ c_low0,
                        const float* __restrict__ h_high0, const float* __restrict__ c_high0,
                        const float* __restrict__ bih_high, const float* __restrict__ bhh_high,
                        const unsigned short* __restrict__ xW,
                        const unsigned short* __restrict__ Whhl,
                        const unsigned short* __restrict__ Wlh,
                        const unsigned short* __restrict__ Wihh,
                        const unsigned short* __restrict__ Whhh,
                        const float* __restrict__ mask, const unsigned* __restrict__ stepflag,
                        unsigned short* __restrict__ hl_buf, unsigned short* __restrict__ hh_buf,
                        unsigned short* __restrict__ hseq, unsigned* bar,
                        float* __restrict__ outS)
{
  __shared__ unsigned short Ws[32*520];   // Whh_low slice in LDS: immune to cache coherence traffic
  __shared__ float hht[64*33];            // cached W_lh @ h_h term
  __shared__ float gb[64*33];             // gate staging
  __shared__ float cl[64*8];
  __shared__ float ch[64*8];
  const int tid = threadIdx.x;
  const int j = blockIdx.x;
  const int d0 = j*8;
  const int wid = tid>>6, lane = tid&63;
  const int lr = lane&15, lk = lane>>4;
  const int mb = wid*16;
  const int eb = tid>>2;            // batch for elementwise
  const int ep = (tid&3)*2;         // dim pair within the WG's 8 dims

  for (int i=tid; i<32*64; i+=256){
    int n = i>>6, cb = i&63;
    int grow = ((n>>3)<<9) + d0 + (n&7);
    *(bf16x8*)&Ws[n*520 + cb*8] = *(const bf16x8*)&Whhl[(size_t)grow*512 + cb*8];
  }
  for (int i=tid; i<512; i+=256){
    int b=i>>3, dd=i&7;
    cl[b*8+dd] = c_low0[b*512 + d0 + dd];
    ch[b*8+dd] = c_high0[b*512 + d0 + dd];
  }
  {
    int gi = eb*512 + d0 + ep;
    st_h2(&hl_buf[gi], f2bf(h_low0[gi]),  f2bf(h_low0[gi+1]));
    st_h2(&hh_buf[gi], f2bf(h_high0[gi]), f2bf(h_high0[gi+1]));
  }
  unsigned gen = 0;
  gbarrier(bar, gen); gen++;
  compute_hht(hh_buf, Wlh, hht, d0, mb, lr, lk);
  __syncthreads();

  int hs = 0;
  for (int t=0; t<T_; t++){
    const int rl = t&1, wl = rl^1;
    const unsigned short* hlr = hl_buf + rl*32768;
    // ---- phase A: low cell ----
    bf16x8 av[16];
    #pragma unroll
    for (int ks=0;ks<16;ks++)
      av[ks] = ld_h8(&hlr[(mb+lr)*512 + ks*32 + lk*8]);
    f32x4 a0 = {0.f,0.f,0.f,0.f}, a1 = {0.f,0.f,0.f,0.f};
    #pragma unroll
    for (int ks=0;ks<16;ks++){
      bf16x8 b0 = *(const bf16x8*)&Ws[lr*520 + ks*32 + lk*8];
      bf16x8 b1 = *(const bf16x8*)&Ws[(16+lr)*520 + ks*32 + lk*8];
      a0 = __builtin_amdgcn_mfma_f32_16x16x32_bf16(av[ks], b0, a0, 0,0,0);
      a1 = __builtin_amdgcn_mfma_f32_16x16x32_bf16(av[ks], b1, a1, 0,0,0);
    }
    #pragma unroll
    for (int r=0;r<4;r++){
      int b = mb + lk*4 + r;
      gb[b*33 + lr]      = a0[r] + hht[b*33 + lr];
      gb[b*33 + 16 + lr] = a1[r] + hht[b*33 + 16 + lr];
    }
    __syncthreads();
    {
      const int b = eb;
      size_t xr = ((size_t)t*64 + b)*2048 + d0 + ep;
      unsigned xi = *(const unsigned*)&xW[xr];
      unsigned xf = *(const unsigned*)&xW[xr + 512];
      unsigned xg = *(const unsigned*)&xW[xr + 1024];
      unsigned xo = *(const unsigned*)&xW[xr + 1536];
      unsigned short hb[2];
      #pragma unroll
      for (int q=0;q<2;q++){
        int dd = ep + q;
        float g_i = gb[b*33 + dd]      + bf2f((unsigned short)(q ? (xi>>16) : (xi&0xffff)));
        float g_f = gb[b*33 + 8 + dd]  + bf2f((unsigned short)(q ? (xf>>16) : (xf&0xffff)));
        float g_g = gb[b*33 + 16 + dd] + bf2f((unsigned short)(q ? (xg>>16) : (xg&0xffff)));
        float g_o = gb[b*33 + 24 + dd] + bf2f((unsigned short)(q ? (xo>>16) : (xo&0xffff)));
        float c = sigm(g_f)*cl[b*8+dd] + sigm(g_i)*tanhf(g_g);
        float h = sigm(g_o)*tanhf(c);
        cl[b*8+dd] = c;
        hb[q] = f2bf(h);
      }
      st_h2(&hl_buf[wl*32768 + b*512 + d0 + ep], hb[0], hb[1]);
      *(unsigned*)&hseq[((size_t)t*64 + b)*512 + d0 + ep] = (unsigned)hb[0] | ((unsigned)hb[1]<<16);
    }
    gbarrier(bar, gen); gen++;
    // ---- phase B: high cell (only when any mask bit set at step t, ~8/256 steps) ----
    unsigned sf = stepflag[t];
    if (sf){
      const unsigned short* hln = hl_buf + wl*32768;
      const unsigned short* hhr = hh_buf + hs*32768;
      bf16x8 avl[16], avh[16];
      #pragma unroll
      for (int ks=0;ks<16;ks++){
        avl[ks] = ld_h8(&hln[(mb+lr)*512 + ks*32 + lk*8]);
        avh[ks] = ld_h8(&hhr[(mb+lr)*512 + ks*32 + lk*8]);
      }
      f32x4 h0 = {0.f,0.f,0.f,0.f}, h1 = {0.f,0.f,0.f,0.f};
      int g0 = ((lr>>3)<<9) + d0 + (lr&7);
      int g1 = 1024 + g0;
      #pragma unroll
      for (int ks=0;ks<16;ks++){
        bf16x8 bi0 = *(const bf16x8*)&Wihh[(size_t)g0*512 + ks*32 + lk*8];
        bf16x8 bi1 = *(const bf16x8*)&Wihh[(size_t)g1*512 + ks*32 + lk*8];
        bf16x8 bh0 = *(const bf16x8*)&Whhh[(size_t)g0*512 + ks*32 + lk*8];
        bf16x8 bh1 = *(const bf16x8*)&Whhh[(size_t)g1*512 + ks*32 + lk*8];
        h0 = __builtin_amdgcn_mfma_f32_16x16x32_bf16(avl[ks], bi0, h0, 0,0,0);
        h0 = __builtin_amdgcn_mfma_f32_16x16x32_bf16(avh[ks], bh0, h0, 0,0,0);
        h1 = __builtin_amdgcn_mfma_f32_16x16x32_bf16(avl[ks], bi1, h1, 0,0,0);
        h1 = __builtin_amdgcn_mfma_f32_16x16x32_bf16(avh[ks], bh1, h1, 0,0,0);
      }
      #pragma unroll
      for (int r=0;r<4;r++){
        int b = mb + lk*4 + r;
        gb[b*33 + lr]      = h0[r];
        gb[b*33 + 16 + lr] = h1[r];
      }
      __syncthreads();
      {
        const int b = eb;
        float m = mask[t*64 + b];
        unsigned hold2 = ld_h2(&hh_buf[hs*32768 + b*512 + d0 + ep]);
        unsigned short hn[2];
        #pragma unroll
        for (int q=0;q<2;q++){
          int dd = ep + q; int d = d0 + dd;
          float g_i = gb[b*33+dd]      + bih_high[d]      + bhh_high[d];
          float g_f = gb[b*33+8+dd]    + bih_high[512+d]  + bhh_high[512+d];
          float g_g = gb[b*33+16+dd]   + bih_high[1024+d] + bhh_high[1024+d];
          float g_o = gb[b*33+24+dd]   + bih_high[1536+d] + bhh_high[1536+d];
          float ct = sigm(g_f)*ch[b*8+dd] + sigm(g_i)*tanhf(g_g);
          float ht = sigm(g_o)*tanhf(ct);
          float hold = bf2f((unsigned short)(q ? (hold2>>16) : (hold2&0xffff)));
          hn[q] = f2bf(m*ht + (1.0f-m)*hold);
          ch[b*8+dd] = m*ct + (1.0f-m)*ch[b*8+dd];
        }
        st_h2(&hh_buf[(hs^1)*32768 + b*512 + d0 + ep], hn[0], hn[1]);
      }
      gbarrier(bar, gen); gen++;
      hs ^= 1;
      compute_hht(hh_buf + hs*32768, Wlh, hht, d0, mb, lr, lk);
      __syncthreads();
    }
  }
  // final states -> f32 (h_l is in slot 0 after t=255; c's are WG-local f32)
  {
    int gi = eb*512 + d0 + ep;
    unsigned hl2 = ld_h2(&hl_buf[gi]);
    unsigned hh2 = ld_h2(&hh_buf[hs*32768 + gi]);
    outS[gi]             = bf2f((unsigned short)(hl2&0xffff));
    outS[gi+1]           = bf2f((unsigned short)(hl2>>16));
    outS[32768 + gi]     = cl[eb*8 + ep];
    outS[32768 + gi + 1] = cl[eb*8 + ep + 1];
    outS[65536 + gi]     = bf2f((unsigned short)(hh2&0xffff));
    outS[65536 + gi + 1] = bf2f((unsigned short)(hh2>>16));
    outS[98304 + gi]     = ch[eb*8 + ep];
    outS[98304 + gi + 1] = ch[eb*8 + ep + 1];
  }
}

extern "C" void kernel_launch(void* const* d_in, const int* in_sizes, int n_in,
                              void* d_out, int out_size, void* d_ws, size_t ws_size,
                              hipStream_t stream)
{
  const int*   in0    = (const int*)  d_in[0];
  const int*   in1    = (const int*)  d_in[1];
  const float* hl0    = (const float*)d_in[2];
  const float* cl0    = (const float*)d_in[3];
  const float* hh0    = (const float*)d_in[4];
  const float* ch0    = (const float*)d_in[5];
  const int*   mtok   = (const int*)  d_in[6];
  const float* emb0   = (const float*)d_in[7];
  const float* emb1   = (const float*)d_in[8];
  const float* Wihl_f = (const float*)d_in[9];
  const float* bihl   = (const float*)d_in[10];
  const float* Whhl_f = (const float*)d_in[11];
  const float* bhhl   = (const float*)d_in[12];
  const float* Wihh_f = (const float*)d_in[13];
  const float* bihh   = (const float*)d_in[14];
  const float* Whhh_f = (const float*)d_in[15];
  const float* bhhh   = (const float*)d_in[16];
  const float* Wd0_f  = (const float*)d_in[17];
  const float* bd0    = (const float*)d_in[18];
  const float* Wd1_f  = (const float*)d_in[19];
  const float* bd1    = (const float*)d_in[20];

  // d_out is FLOAT. Layout (floats): dec0 [B,T,2048] @0 (33.5M), dec1 [B,T,512]
  // @33554432 (8.4M), states @41943040 (4x32768).
  float* dout = (float*)d_out;
  // bf16 scratch aliased into d_out (dead before the dec GEMMs write there):
  // xW (64 MiB) in dec0's 128 MiB region; E (16 MiB) in dec1's 32 MiB region.
  unsigned short* xW = (unsigned short*)dout;
  unsigned short* E  = (unsigned short*)(dout + 33554432);

  char* ws = (char*)d_ws;
  unsigned short* hseq = (unsigned short*)(ws + 0);          // [16384][512] bf16, 16 MiB
  unsigned short* W0   = (unsigned short*)(ws + 16777216);
  unsigned short* Wlh  = (unsigned short*)(ws + 18874368);
  unsigned short* Whhl = (unsigned short*)(ws + 20971520);
  unsigned short* Wihh = (unsigned short*)(ws + 23068672);
  unsigned short* Whhh = (unsigned short*)(ws + 25165824);
  unsigned short* Wd0  = (unsigned short*)(ws + 27262976);
  unsigned short* Wd1  = (unsigned short*)(ws + 29360128);
  unsigned short* hlb  = (unsigned short*)(ws + 29884416);   // [2][64][512] bf16
  unsigned short* hhb  = (unsigned short*)(ws + 30015488);   // [2][64][512] bf16
  float*          mask = (float*)    (ws + 30146560);        // [256][64]
  unsigned*       sflg = (unsigned*) (ws + 30212096);        // [256]
  unsigned*       bar  = (unsigned*) (ws + 30213120);

  k_prep<<<2048, 256, 0, stream>>>(in0,in1,mtok,emb0,emb1,Wihl_f,Whhl_f,Wihh_f,Whhh_f,Wd0_f,Wd1_f,
                                   W0,Wlh,Whhl,Wihh,Whhh,Wd0,Wd1,E,mask,sflg,bar);
  dim3 g1(128,16);
  k_gemm<<<g1, 256, 0, stream>>>(E, W0, bihl, bhhl, xW, nullptr, 2048, 0);
  k_recur<<<NWG, 256, 0, stream>>>(hl0,cl0,hh0,ch0,bihh,bhhh,xW,Whhl,Wlh,Wihh,Whhh,
                                   mask,sflg,hlb,hhb,hseq,bar,dout + 41943040);
  k_gemm<<<g1, 256, 0, stream>>>(hseq, Wd0, bd0, nullptr, nullptr, dout, 2048, 1);
  dim3 g2(128,4);
  k_gemm<<<g2, 256, 0, stream>>>(hseq, Wd1, bd1, nullptr, nullptr, dout + 33554432, 512, 1);
}